// Round 2
// baseline (450.228 us; speedup 1.0000x reference)
//
#include <hip/hip_runtime.h>
#include <stdint.h>

#define CIN 256
#define COUT 128
#define SDIM 512
#define NB 16

// x_pad geometry: [b][66 rows][66 cols][256 ci] bf16
#define XP_RSTRIDE 16896          // 66*256
#define XP_BSTRIDE 1115136        // 66*66*256
// A geometry: [b][512 m][2304 k] bf16
#define A_BSTRIDE (512*2304)

typedef __attribute__((ext_vector_type(8))) short short8;
typedef __attribute__((ext_vector_type(4))) float f32x4;

__device__ __forceinline__ float bf2f(unsigned short h) {
  union { unsigned int u; float f; } v; v.u = ((unsigned int)h) << 16; return v.f;
}
__device__ __forceinline__ unsigned short f2bf(float f) {
  union { float f; unsigned int u; } v; v.f = f;
  return (unsigned short)((v.u + 0x7fffu + ((v.u >> 16) & 1u)) >> 16);
}
__device__ __forceinline__ void gll16(const void* g, void* l) {
  __builtin_amdgcn_global_load_lds(
      (const __attribute__((address_space(1))) unsigned int*)g,
      (__attribute__((address_space(3))) unsigned int*)l, 16, 0, 0);
}

// ---------------- kernel 0: dtype detector ----------------
// f32 input read as u16: even-index halves are mantissa bits -> uniform exponent
// field (~21% in sane range). bf16 input: real N(0,1) values (~100% sane).
__global__ __launch_bounds__(256) void k_detect(
    const unsigned short* __restrict__ xr, int* __restrict__ flag) {
  __shared__ int red[4];
  int t = threadIdx.x, cnt = 0;
  for (int i = t; i < 8192; i += 256) {
    int e = (xr[2*i] >> 7) & 0xff;
    cnt += (e > 90 && e < 145) ? 1 : 0;
  }
  #pragma unroll
  for (int off = 32; off > 0; off >>= 1) cnt += __shfl_down(cnt, off);
  if ((t & 63) == 0) red[t >> 6] = cnt;
  __syncthreads();
  if (t == 0) *flag = (red[0] + red[1] + red[2] + red[3] < 5000) ? 1 : 0;  // 1 = f32
}

// ---------------- kernel 1: s = style @ mod_w^T + mod_b ----------------
__global__ __launch_bounds__(256) void k_style(
    const void* __restrict__ style_v, const void* __restrict__ mod_w_v,
    const void* __restrict__ mod_b_v, const int* __restrict__ flag,
    float* __restrict__ s_out) {                // [16][256] f32
  __shared__ float st[SDIM];
  int b = blockIdx.x, t = threadIdx.x;
  int isf = *flag;
  float acc;
  if (!isf) {
    const unsigned short* style = (const unsigned short*)style_v;
    const unsigned short* mod_w = (const unsigned short*)mod_w_v;
    const unsigned short* mod_b = (const unsigned short*)mod_b_v;
    st[t]       = bf2f(style[b*SDIM + t]);
    st[t + 256] = bf2f(style[b*SDIM + t + 256]);
    __syncthreads();
    const uint4* wr = (const uint4*)(mod_w + (size_t)t*SDIM);
    acc = bf2f(mod_b[t]);
    #pragma unroll 4
    for (int s8 = 0; s8 < SDIM/8; ++s8) {
      uint4 p = wr[s8];
      int sb = s8*8;
      acc += bf2f((unsigned short)(p.x & 0xffff))*st[sb]
           + bf2f((unsigned short)(p.x >> 16))   *st[sb+1]
           + bf2f((unsigned short)(p.y & 0xffff))*st[sb+2]
           + bf2f((unsigned short)(p.y >> 16))   *st[sb+3]
           + bf2f((unsigned short)(p.z & 0xffff))*st[sb+4]
           + bf2f((unsigned short)(p.z >> 16))   *st[sb+5]
           + bf2f((unsigned short)(p.w & 0xffff))*st[sb+6]
           + bf2f((unsigned short)(p.w >> 16))   *st[sb+7];
    }
  } else {
    const float* style = (const float*)style_v;
    const float* mod_w = (const float*)mod_w_v;
    const float* mod_b = (const float*)mod_b_v;
    st[t]       = style[b*SDIM + t];
    st[t + 256] = style[b*SDIM + t + 256];
    __syncthreads();
    const float4* wr = (const float4*)(mod_w + (size_t)t*SDIM);
    acc = mod_b[t];
    #pragma unroll 4
    for (int s4 = 0; s4 < SDIM/4; ++s4) {
      float4 p = wr[s4];
      int sb = s4*4;
      acc += p.x*st[sb] + p.y*st[sb+1] + p.z*st[sb+2] + p.w*st[sb+3];
    }
  }
  s_out[b*CIN + t] = acc;
}

// ---------------- kernel 2: modulate+demod+blur-fold -> A[b][m][k] ----------------
// m = py*256 + co*2 + px ; k = tap*256 + ci, tap = (dh+1)*3+(dw+1)
// A value = C6[py-2dh+2][px-2dw+2], C6[ty][tx] = sum_{ay,ax} w[ay][ax]*F[ay-ty+3]*F[ax-tx+3]
__global__ __launch_bounds__(256) void k_weights(
    const void* __restrict__ weight_v,          // [128][256][3][3]
    const float* __restrict__ s_in,             // [16][256]
    const int* __restrict__ flag,
    unsigned short* __restrict__ Aw) {
  int co = blockIdx.x, b = blockIdx.y, ci = threadIdx.x;
  int isf = *flag;
  float sm = 0.0208333333333333f * s_in[b*CIN + ci];   // 1/48 = 1/sqrt(2304)
  float w9[9]; float ss = 0.f;
  if (!isf) {
    const unsigned short* wp = (const unsigned short*)weight_v + ((size_t)co*CIN + ci)*9;
    #pragma unroll
    for (int k = 0; k < 9; ++k) { float v = bf2f(wp[k]) * sm; w9[k] = v; ss += v*v; }
  } else {
    const float* wp = (const float*)weight_v + ((size_t)co*CIN + ci)*9;
    #pragma unroll
    for (int k = 0; k < 9; ++k) { float v = wp[k] * sm; w9[k] = v; ss += v*v; }
  }
  #pragma unroll
  for (int off = 32; off > 0; off >>= 1) ss += __shfl_down(ss, off);
  __shared__ float red[4];
  if ((ci & 63) == 0) red[ci >> 6] = ss;
  __syncthreads();
  float demod = rsqrtf(red[0] + red[1] + red[2] + red[3] + 1e-8f);
  #pragma unroll
  for (int k = 0; k < 9; ++k) w9[k] *= demod;
  const float F[4] = {0.25f, 0.75f, 0.75f, 0.25f};   // [1,3,3,1]/4 (blur, x4 up-gain folded)
  float C6[6][6];
  #pragma unroll
  for (int ty = 0; ty < 6; ++ty) {
    #pragma unroll
    for (int tx = 0; tx < 6; ++tx) {
      float acc = 0.f;
      #pragma unroll
      for (int ay = 0; ay < 3; ++ay) {
        int fy = ay - ty + 3;
        if (fy < 0 || fy > 3) continue;
        float ra = 0.f;
        #pragma unroll
        for (int ax = 0; ax < 3; ++ax) {
          int fx = ax - tx + 3;
          if (fx < 0 || fx > 3) continue;
          ra += w9[ay*3 + ax] * F[fx];
        }
        acc += ra * F[fy];
      }
      C6[ty][tx] = acc;
    }
  }
  unsigned short* Ab = Aw + (size_t)b*A_BSTRIDE;
  #pragma unroll
  for (int py = 0; py < 2; ++py) {
    #pragma unroll
    for (int px = 0; px < 2; ++px) {
      unsigned short* Am = Ab + (size_t)(py*256 + co*2 + px)*2304 + ci;
      #pragma unroll
      for (int dh = -1; dh <= 1; ++dh) {
        #pragma unroll
        for (int dw = -1; dw <= 1; ++dw) {
          int tap = (dh+1)*3 + (dw+1);
          Am[tap*256] = f2bf(C6[py - 2*dh + 2][px - 2*dw + 2]);
        }
      }
    }
  }
}

// ---------------- kernel 3: x -> x_pad[b][r+1][c+1][ci] bf16, zero halo ----------------
__global__ __launch_bounds__(256) void k_transpose(
    const void* __restrict__ x_v,   // [16][256][64][64] bf16 or f32
    const int* __restrict__ flag,
    unsigned short* __restrict__ xp) {
  int r_out = blockIdx.x, b = blockIdx.y, t = threadIdx.x;
  unsigned short* rp = xp + (size_t)b*XP_BSTRIDE + (size_t)r_out*XP_RSTRIDE;
  int r_in = r_out - 1;
  if (r_in < 0 || r_in >= 64) {          // border rows: all zero
    uint4 z = make_uint4(0,0,0,0);
    #pragma unroll
    for (int i = 0; i < 9; ++i) {
      int idx = i*256 + t;
      if (idx < 2112) ((uint4*)rp)[idx] = z;   // 16896 elems = 2112 uint4
    }
    return;
  }
  if (t < 64) {                           // border cols 0 and 65: zero
    uint4 z = make_uint4(0,0,0,0);
    int col = (t < 32) ? 0 : 65;
    ((uint4*)(rp + col*256))[t & 31] = z;
  }
  int isf = *flag;
  __shared__ __align__(16) unsigned short lds[64*72];
  int ci_l = t >> 2, cp = t & 3;          // load mapping
  int c = t >> 2, jg = t & 3;             // store mapping
  for (int g4 = 0; g4 < 4; ++g4) {        // 4 ci-groups of 64
    int ci0 = g4 * 64;
    size_t eoff = ((size_t)b*CIN + ci0 + ci_l)*4096 + (size_t)r_in*64 + cp*16;
    union { unsigned short s[16]; uint4 q[2]; } u;
    if (!isf) {
      const uint4* src = (const uint4*)((const unsigned short*)x_v + eoff);
      u.q[0] = src[0]; u.q[1] = src[1];
    } else {
      const float4* srcf = (const float4*)((const float*)x_v + eoff);
      float4 f0 = srcf[0], f1 = srcf[1], f2 = srcf[2], f3 = srcf[3];
      u.s[0]=f2bf(f0.x); u.s[1]=f2bf(f0.y); u.s[2]=f2bf(f0.z); u.s[3]=f2bf(f0.w);
      u.s[4]=f2bf(f1.x); u.s[5]=f2bf(f1.y); u.s[6]=f2bf(f1.z); u.s[7]=f2bf(f1.w);
      u.s[8]=f2bf(f2.x); u.s[9]=f2bf(f2.y); u.s[10]=f2bf(f2.z); u.s[11]=f2bf(f2.w);
      u.s[12]=f2bf(f3.x); u.s[13]=f2bf(f3.y); u.s[14]=f2bf(f3.z); u.s[15]=f2bf(f3.w);
    }
    if (g4) __syncthreads();
    *(uint4*)&lds[ci_l*72 + cp*16]     = u.q[0];
    *(uint4*)&lds[ci_l*72 + cp*16 + 8] = u.q[1];
    __syncthreads();
    unsigned short ov[16] __attribute__((aligned(16)));
    #pragma unroll
    for (int j = 0; j < 16; ++j) ov[j] = lds[(jg*16 + j)*72 + c];
    uint4* dst = (uint4*)(rp + (size_t)(c+1)*256 + ci0 + jg*16);
    dst[0] = *(const uint4*)&ov[0];
    dst[1] = *(const uint4*)&ov[8];
  }
}

// ---------------- kernel 4: implicit-GEMM subpixel conv (m97 structure) ----------------
__global__ __launch_bounds__(256) void k_gemm(
    const unsigned short* __restrict__ Aw,
    const unsigned short* __restrict__ xp,
    const int* __restrict__ flag,
    void* __restrict__ out) {
  __shared__ __align__(16) unsigned short As[128*32];
  __shared__ __align__(16) unsigned short Bs[128*32];
  int g = blockIdx.x;
  int b  = ((g & 7) << 1) | ((g >> 3) & 1);   // 2 batch samples per XCD
  int mt = (g >> 4) & 3;
  int nt = g >> 6;                 // 0..31
  int yy0 = nt << 1;
  int t = threadIdx.x;
  int wave = t >> 6, lane = t & 63;
  int row = t >> 2, part = t & 3;

  // diagnostic guard: stale-LDS reads become 0, not junk
  {
    uint4 z = make_uint4(0,0,0,0);
    ((uint4*)As)[t] = z; ((uint4*)As)[t+256] = z;
    ((uint4*)Bs)[t] = z; ((uint4*)Bs)[t+256] = z;
  }
  __syncthreads();

  const unsigned short* Abase = Aw + (size_t)b*A_BSTRIDE + (size_t)(mt*128)*2304 + part*8;
  const unsigned short* pA0 = Abase + (size_t)row*2304;
  const unsigned short* pA1 = Abase + (size_t)(row + 64)*2304;
  const unsigned short* Xb = xp + (size_t)b*XP_BSTRIDE + part*8;
  const unsigned short* pB0 = Xb + (size_t)(yy0 + 1)*XP_RSTRIDE + (size_t)(row + 1)*256; // ry=0
  const unsigned short* pB1 = Xb + (size_t)(yy0 + 2)*XP_RSTRIDE + (size_t)(row + 1)*256; // ry=1
  unsigned short* lA0 = &As[row*32 + part*8];
  unsigned short* lA1 = &As[(row + 64)*32 + part*8];
  unsigned short* lB0 = &Bs[row*32 + part*8];
  unsigned short* lB1 = &Bs[(row + 64)*32 + part*8];

  f32x4 acc[4][4];
  #pragma unroll
  for (int i = 0; i < 4; ++i)
    #pragma unroll
    for (int j = 0; j < 4; ++j)
      acc[i][j] = (f32x4){0.f, 0.f, 0.f, 0.f};

  int mb = (wave >> 1) << 6;   // wave m-base
  int nb = (wave & 1) << 6;    // wave n-base (ry = wave&1)
  int l15 = lane & 15, q = lane >> 4;

  for (int s = 0; s < 72; ++s) {
    int tap = s >> 3;
    int dh = tap/3 - 1, dw = tap - (tap/3)*3 - 1;
    int boff = dh*XP_RSTRIDE + dw*256 + ((s & 7) << 5);  // wave-uniform elem offset
    int aoff = s << 5;
    gll16(pA0 + aoff, lA0);
    gll16(pA1 + aoff, lA1);
    gll16(pB0 + boff, lB0);
    gll16(pB1 + boff, lB1);
    __syncthreads();
    short8 af[4], bfv[4];
    #pragma unroll
    for (int i = 0; i < 4; ++i)
      af[i] = *(const short8*)&As[(mb + i*16 + l15)*32 + q*8];
    #pragma unroll
    for (int j = 0; j < 4; ++j)
      bfv[j] = *(const short8*)&Bs[(nb + j*16 + l15)*32 + q*8];
    #pragma unroll
    for (int i = 0; i < 4; ++i)
      #pragma unroll
      for (int j = 0; j < 4; ++j)
        acc[i][j] = __builtin_amdgcn_mfma_f32_16x16x32_bf16(af[i], bfv[j], acc[i][j], 0, 0, 0);
    __syncthreads();
  }

  // epilogue: D row m = q*4+reg; m = py*256 + co*2 + px
  int isf = *flag;
  int py = mt >> 1;
  int ry = wave & 1;
  int y = ((yy0 + ry) << 1) + py;
  int cobase = ((mt & 1) << 6) + ((wave >> 1) << 5);
  #pragma unroll
  for (int i = 0; i < 4; ++i) {
    #pragma unroll
    for (int rr = 0; rr < 2; ++rr) {
      int co = cobase + i*8 + q*2 + rr;
      size_t obase = (((size_t)b*COUT + co)*128 + y)*64;
      if (!isf) {
        unsigned int* outp = (unsigned int*)out;
        #pragma unroll
        for (int j = 0; j < 4; ++j) {
          unsigned int pk = (unsigned int)f2bf(acc[i][j][rr*2])
                          | ((unsigned int)f2bf(acc[i][j][rr*2 + 1]) << 16);
          outp[obase + j*16 + l15] = pk;
        }
      } else {
        float2* outp = (float2*)out;
        #pragma unroll
        for (int j = 0; j < 4; ++j)
          outp[obase + j*16 + l15] = make_float2(acc[i][j][rr*2], acc[i][j][rr*2 + 1]);
      }
    }
  }
}

extern "C" void kernel_launch(void* const* d_in, const int* in_sizes, int n_in,
                              void* d_out, int out_size, void* d_ws, size_t ws_size,
                              hipStream_t stream) {
  const void* x      = d_in[0];
  const void* style  = d_in[1];
  const void* weight = d_in[2];
  const void* mod_w  = d_in[3];
  const void* mod_b  = d_in[4];
  char* ws = (char*)d_ws;
  int* flag           = (int*)ws;                                     // 4 B
  float* s_buf        = (float*)(ws + 1024);                          // 16 KB
  unsigned short* Aw  = (unsigned short*)(ws + 32768);                // 37,748,736 B
  unsigned short* xpd = (unsigned short*)(ws + 32768 + 37748736);     // 35,684,352 B

  k_detect   <<<1, 256, 0, stream>>>((const unsigned short*)x, flag);
  k_style    <<<NB, 256, 0, stream>>>(style, mod_w, mod_b, flag, s_buf);
  k_weights  <<<dim3(COUT, NB), 256, 0, stream>>>(weight, s_buf, flag, Aw);
  k_transpose<<<dim3(66, NB), 256, 0, stream>>>(x, flag, xpd);
  k_gemm     <<<2048, 256, 0, stream>>>(Aw, xpd, flag, d_out);
}

// Round 3
// 430.163 us; speedup vs baseline: 1.0466x; 1.0466x over previous
//
#include <hip/hip_runtime.h>
#include <stdint.h>

#define CIN 256
#define COUT 128
#define SDIM 512
#define NB 16

// x_pad geometry: [b][66 rows][66 cols][256 ci] bf16
#define XP_RSTRIDE 16896          // 66*256
#define XP_BSTRIDE 1115136        // 66*66*256
// A geometry: [b][512 m][2304 k] bf16
#define A_BSTRIDE (512*2304)

typedef __attribute__((ext_vector_type(8))) short short8;
typedef __attribute__((ext_vector_type(4))) float f32x4;

__device__ __forceinline__ float bf2f(unsigned short h) {
  union { unsigned int u; float f; } v; v.u = ((unsigned int)h) << 16; return v.f;
}
__device__ __forceinline__ unsigned short f2bf(float f) {
  union { float f; unsigned int u; } v; v.f = f;
  return (unsigned short)((v.u + 0x7fffu + ((v.u >> 16) & 1u)) >> 16);
}
__device__ __forceinline__ void gll16(const void* g, void* l) {
  __builtin_amdgcn_global_load_lds(
      (const __attribute__((address_space(1))) unsigned int*)g,
      (__attribute__((address_space(3))) unsigned int*)l, 16, 0, 0);
}

// ---------------- kernel 0: dtype detector ----------------
__global__ __launch_bounds__(256) void k_detect(
    const unsigned short* __restrict__ xr, int* __restrict__ flag) {
  __shared__ int red[4];
  int t = threadIdx.x, cnt = 0;
  for (int i = t; i < 8192; i += 256) {
    int e = (xr[2*i] >> 7) & 0xff;
    cnt += (e > 90 && e < 145) ? 1 : 0;
  }
  #pragma unroll
  for (int off = 32; off > 0; off >>= 1) cnt += __shfl_down(cnt, off);
  if ((t & 63) == 0) red[t >> 6] = cnt;
  __syncthreads();
  if (t == 0) *flag = (red[0] + red[1] + red[2] + red[3] < 5000) ? 1 : 0;  // 1 = f32
}

// ---------------- kernel 1: s = style @ mod_w^T + mod_b ----------------
__global__ __launch_bounds__(256) void k_style(
    const void* __restrict__ style_v, const void* __restrict__ mod_w_v,
    const void* __restrict__ mod_b_v, const int* __restrict__ flag,
    float* __restrict__ s_out) {                // [16][256] f32
  __shared__ float st[SDIM];
  int b = blockIdx.x, t = threadIdx.x;
  int isf = *flag;
  float acc;
  if (!isf) {
    const unsigned short* style = (const unsigned short*)style_v;
    const unsigned short* mod_w = (const unsigned short*)mod_w_v;
    const unsigned short* mod_b = (const unsigned short*)mod_b_v;
    st[t]       = bf2f(style[b*SDIM + t]);
    st[t + 256] = bf2f(style[b*SDIM + t + 256]);
    __syncthreads();
    const uint4* wr = (const uint4*)(mod_w + (size_t)t*SDIM);
    acc = bf2f(mod_b[t]);
    #pragma unroll 4
    for (int s8 = 0; s8 < SDIM/8; ++s8) {
      uint4 p = wr[s8];
      int sb = s8*8;
      acc += bf2f((unsigned short)(p.x & 0xffff))*st[sb]
           + bf2f((unsigned short)(p.x >> 16))   *st[sb+1]
           + bf2f((unsigned short)(p.y & 0xffff))*st[sb+2]
           + bf2f((unsigned short)(p.y >> 16))   *st[sb+3]
           + bf2f((unsigned short)(p.z & 0xffff))*st[sb+4]
           + bf2f((unsigned short)(p.z >> 16))   *st[sb+5]
           + bf2f((unsigned short)(p.w & 0xffff))*st[sb+6]
           + bf2f((unsigned short)(p.w >> 16))   *st[sb+7];
    }
  } else {
    const float* style = (const float*)style_v;
    const float* mod_w = (const float*)mod_w_v;
    const float* mod_b = (const float*)mod_b_v;
    st[t]       = style[b*SDIM + t];
    st[t + 256] = style[b*SDIM + t + 256];
    __syncthreads();
    const float4* wr = (const float4*)(mod_w + (size_t)t*SDIM);
    acc = mod_b[t];
    #pragma unroll 4
    for (int s4 = 0; s4 < SDIM/4; ++s4) {
      float4 p = wr[s4];
      int sb = s4*4;
      acc += p.x*st[sb] + p.y*st[sb+1] + p.z*st[sb+2] + p.w*st[sb+3];
    }
  }
  s_out[b*CIN + t] = acc;
}

// ---------------- kernel 2: modulate+demod+blur-fold -> A[b][m][k] ----------------
// m = py*256 + co*2 + px ; k = tap*256 + ci, tap = (dh+1)*3+(dw+1)
__global__ __launch_bounds__(256) void k_weights(
    const void* __restrict__ weight_v,          // [128][256][3][3]
    const float* __restrict__ s_in,             // [16][256]
    const int* __restrict__ flag,
    unsigned short* __restrict__ Aw) {
  int co = blockIdx.x, b = blockIdx.y, ci = threadIdx.x;
  int isf = *flag;
  float sm = 0.0208333333333333f * s_in[b*CIN + ci];   // 1/48 = 1/sqrt(2304)
  float w9[9]; float ss = 0.f;
  if (!isf) {
    const unsigned short* wp = (const unsigned short*)weight_v + ((size_t)co*CIN + ci)*9;
    #pragma unroll
    for (int k = 0; k < 9; ++k) { float v = bf2f(wp[k]) * sm; w9[k] = v; ss += v*v; }
  } else {
    const float* wp = (const float*)weight_v + ((size_t)co*CIN + ci)*9;
    #pragma unroll
    for (int k = 0; k < 9; ++k) { float v = wp[k] * sm; w9[k] = v; ss += v*v; }
  }
  #pragma unroll
  for (int off = 32; off > 0; off >>= 1) ss += __shfl_down(ss, off);
  __shared__ float red[4];
  if ((ci & 63) == 0) red[ci >> 6] = ss;
  __syncthreads();
  float demod = rsqrtf(red[0] + red[1] + red[2] + red[3] + 1e-8f);
  #pragma unroll
  for (int k = 0; k < 9; ++k) w9[k] *= demod;
  const float F[4] = {0.25f, 0.75f, 0.75f, 0.25f};   // [1,3,3,1]/4 (x4 up-gain folded)
  float C6[6][6];
  #pragma unroll
  for (int ty = 0; ty < 6; ++ty) {
    #pragma unroll
    for (int tx = 0; tx < 6; ++tx) {
      float acc = 0.f;
      #pragma unroll
      for (int ay = 0; ay < 3; ++ay) {
        int fy = ay - ty + 3;
        if (fy < 0 || fy > 3) continue;
        float ra = 0.f;
        #pragma unroll
        for (int ax = 0; ax < 3; ++ax) {
          int fx = ax - tx + 3;
          if (fx < 0 || fx > 3) continue;
          ra += w9[ay*3 + ax] * F[fx];
        }
        acc += ra * F[fy];
      }
      C6[ty][tx] = acc;
    }
  }
  unsigned short* Ab = Aw + (size_t)b*A_BSTRIDE;
  #pragma unroll
  for (int py = 0; py < 2; ++py) {
    #pragma unroll
    for (int px = 0; px < 2; ++px) {
      unsigned short* Am = Ab + (size_t)(py*256 + co*2 + px)*2304 + ci;
      #pragma unroll
      for (int dh = -1; dh <= 1; ++dh) {
        #pragma unroll
        for (int dw = -1; dw <= 1; ++dw) {
          int tap = (dh+1)*3 + (dw+1);
          Am[tap*256] = f2bf(C6[py - 2*dh + 2][px - 2*dw + 2]);
        }
      }
    }
  }
}

// ---------------- kernel 3: x -> x_pad[b][r+1][c+1][ci] bf16, zero halo ----------------
// v2: dword-packed ci-pairs through LDS; conflict-free (2-way) both directions.
__global__ __launch_bounds__(256) void k_transpose(
    const void* __restrict__ x_v,   // [16][256][64][64] bf16 or f32
    const int* __restrict__ flag,
    unsigned short* __restrict__ xp) {
  int r_out = blockIdx.x, b = blockIdx.y, t = threadIdx.x;
  unsigned short* rp = xp + (size_t)b*XP_BSTRIDE + (size_t)r_out*XP_RSTRIDE;
  int r_in = r_out - 1;
  if (r_in < 0 || r_in >= 64) {          // border rows: all zero
    uint4 z = make_uint4(0,0,0,0);
    #pragma unroll
    for (int i = 0; i < 9; ++i) {
      int idx = i*256 + t;
      if (idx < 2112) ((uint4*)rp)[idx] = z;   // 16896 u16 = 2112 uint4
    }
    return;
  }
  if (t < 64) {                           // border cols 0 and 65: zero
    uint4 z = make_uint4(0,0,0,0);
    int col = (t < 32) ? 0 : 65;
    ((uint4*)(rp + col*256))[t & 31] = z;
  }
  int isf = *flag;
  __shared__ unsigned int lds32[64*33];   // [c 64][ci-pair 32], stride 33 dwords
  int tci = t >> 3;                       // ci-pair index 0..31
  int tc8 = t & 7;                        // c-octet 0..7
  int cS  = t >> 2;                       // store-side c 0..63
  int jg  = t & 3;                        // store-side ci chunk (16 ci)
  for (int g4 = 0; g4 < 4; ++g4) {
    int ci0 = g4 * 64;
    int ci = ci0 + tci*2;
    size_t base = (((size_t)b*CIN + ci)*64 + r_in)*64 + tc8*8;
    unsigned int v[8];
    if (isf) {
      const float* s0 = (const float*)x_v + base;
      const float* s1 = s0 + 4096;
      float4 a0 = ((const float4*)s0)[0], a1 = ((const float4*)s0)[1];
      float4 b0 = ((const float4*)s1)[0], b1 = ((const float4*)s1)[1];
      v[0] = f2bf(a0.x) | ((unsigned int)f2bf(b0.x) << 16);
      v[1] = f2bf(a0.y) | ((unsigned int)f2bf(b0.y) << 16);
      v[2] = f2bf(a0.z) | ((unsigned int)f2bf(b0.z) << 16);
      v[3] = f2bf(a0.w) | ((unsigned int)f2bf(b0.w) << 16);
      v[4] = f2bf(a1.x) | ((unsigned int)f2bf(b1.x) << 16);
      v[5] = f2bf(a1.y) | ((unsigned int)f2bf(b1.y) << 16);
      v[6] = f2bf(a1.z) | ((unsigned int)f2bf(b1.z) << 16);
      v[7] = f2bf(a1.w) | ((unsigned int)f2bf(b1.w) << 16);
    } else {
      const unsigned short* s0 = (const unsigned short*)x_v + base;
      const unsigned short* s1 = s0 + 4096;
      union { uint4 q; unsigned short h[8]; } u0, u1;
      u0.q = *(const uint4*)s0; u1.q = *(const uint4*)s1;
      #pragma unroll
      for (int j = 0; j < 8; ++j)
        v[j] = (unsigned int)u0.h[j] | ((unsigned int)u1.h[j] << 16);
    }
    if (g4) __syncthreads();
    #pragma unroll
    for (int j = 0; j < 8; ++j)
      lds32[(tc8*8 + j)*33 + tci] = v[j];
    __syncthreads();
    union { unsigned int o[8]; uint4 q[2]; } ob;
    #pragma unroll
    for (int w = 0; w < 8; ++w)
      ob.o[w] = lds32[cS*33 + jg*8 + w];
    uint4* dst = (uint4*)(rp + (size_t)(cS+1)*256 + ci0 + jg*16);
    dst[0] = ob.q[0];
    dst[1] = ob.q[1];
  }
}

// ---------------- kernel 4: implicit-GEMM subpixel conv ----------------
// v2: XOR-swizzled k-chunk staging (kills 8-way frag-read conflicts),
// tap-outer/unrolled-inner K loop (offset-folded global_load_lds).
__global__ __launch_bounds__(256) void k_gemm(
    const unsigned short* __restrict__ Aw,
    const unsigned short* __restrict__ xp,
    const int* __restrict__ flag,
    void* __restrict__ out) {
  __shared__ __align__(16) unsigned short As[128*32];
  __shared__ __align__(16) unsigned short Bs[128*32];
  int g = blockIdx.x;
  int b  = ((g & 7) << 1) | ((g >> 3) & 1);   // 2 batch samples per XCD
  int mt = (g >> 4) & 3;
  int nt = g >> 6;                 // 0..31
  int yy0 = nt << 1;
  int t = threadIdx.x;
  int wave = t >> 6, lane = t & 63;
  int row = t >> 2, part = t & 3;
  int isf = *flag;

  // source-permuted staging: physical slot (row, part) holds k-chunk part^((row>>2)&3)
  int partS = part ^ ((row >> 2) & 3);
  const unsigned short* pA0 = Aw + (size_t)b*A_BSTRIDE + (size_t)(mt*128 + row)*2304 + partS*8;
  const unsigned short* pA1 = pA0 + (size_t)64*2304;
  const unsigned short* pB0 = xp + (size_t)b*XP_BSTRIDE + (size_t)(yy0 + 1)*XP_RSTRIDE
                              + (size_t)(row + 1)*256 + partS*8;
  const unsigned short* pB1 = pB0 + XP_RSTRIDE;
  unsigned short* lA0 = &As[row*32 + part*8];
  unsigned short* lA1 = &As[(row + 64)*32 + part*8];
  unsigned short* lB0 = &Bs[row*32 + part*8];
  unsigned short* lB1 = &Bs[(row + 64)*32 + part*8];

  f32x4 acc[4][4];
  #pragma unroll
  for (int i = 0; i < 4; ++i)
    #pragma unroll
    for (int j = 0; j < 4; ++j)
      acc[i][j] = (f32x4){0.f, 0.f, 0.f, 0.f};

  int mb = (wave >> 1) << 6;   // wave m-base
  int nb = (wave & 1) << 6;    // wave n-base (ry = wave&1)
  int l15 = lane & 15, q = lane >> 4;
  int qs = q ^ ((l15 >> 2) & 3);          // frag-read swizzle (invariant in i, mb)

  for (int tap = 0; tap < 9; ++tap) {
    int dh = (tap >= 6) ? 1 : ((tap >= 3) ? 0 : -1);
    int dwx = tap - (dh + 1)*3 - 1;
    const unsigned short* a0 = pA0 + tap*256;
    const unsigned short* a1 = pA1 + tap*256;
    const unsigned short* b0 = pB0 + dh*XP_RSTRIDE + dwx*256;
    const unsigned short* b1 = b0 + XP_RSTRIDE;
    #pragma unroll
    for (int kk = 0; kk < 8; ++kk) {
      gll16(a0 + kk*32, lA0);
      gll16(a1 + kk*32, lA1);
      gll16(b0 + kk*32, lB0);
      gll16(b1 + kk*32, lB1);
      __syncthreads();
      short8 af[4], bfv[4];
      #pragma unroll
      for (int i = 0; i < 4; ++i)
        af[i] = *(const short8*)&As[(mb + i*16 + l15)*32 + qs*8];
      #pragma unroll
      for (int j = 0; j < 4; ++j)
        bfv[j] = *(const short8*)&Bs[(nb + j*16 + l15)*32 + qs*8];
      #pragma unroll
      for (int i = 0; i < 4; ++i)
        #pragma unroll
        for (int j = 0; j < 4; ++j)
          acc[i][j] = __builtin_amdgcn_mfma_f32_16x16x32_bf16(af[i], bfv[j], acc[i][j], 0, 0, 0);
      __syncthreads();
    }
  }

  // epilogue: D row m = q*4+reg; m = py*256 + co*2 + px
  int py = mt >> 1;
  int ry = wave & 1;
  int y = ((yy0 + ry) << 1) + py;
  int cobase = ((mt & 1) << 6) + ((wave >> 1) << 5);
  #pragma unroll
  for (int i = 0; i < 4; ++i) {
    #pragma unroll
    for (int rr = 0; rr < 2; ++rr) {
      int co = cobase + i*8 + q*2 + rr;
      size_t obase = (((size_t)b*COUT + co)*128 + y)*64;
      if (!isf) {
        unsigned int* outp = (unsigned int*)out;
        #pragma unroll
        for (int j = 0; j < 4; ++j) {
          unsigned int pk = (unsigned int)f2bf(acc[i][j][rr*2])
                          | ((unsigned int)f2bf(acc[i][j][rr*2 + 1]) << 16);
          outp[obase + j*16 + l15] = pk;
        }
      } else {
        float2* outp = (float2*)out;
        #pragma unroll
        for (int j = 0; j < 4; ++j)
          outp[obase + j*16 + l15] = make_float2(acc[i][j][rr*2], acc[i][j][rr*2 + 1]);
      }
    }
  }
}

extern "C" void kernel_launch(void* const* d_in, const int* in_sizes, int n_in,
                              void* d_out, int out_size, void* d_ws, size_t ws_size,
                              hipStream_t stream) {
  const void* x      = d_in[0];
  const void* style  = d_in[1];
  const void* weight = d_in[2];
  const void* mod_w  = d_in[3];
  const void* mod_b  = d_in[4];
  char* ws = (char*)d_ws;
  int* flag           = (int*)ws;                                     // 4 B
  float* s_buf        = (float*)(ws + 1024);                          // 16 KB
  unsigned short* Aw  = (unsigned short*)(ws + 32768);                // 37,748,736 B
  unsigned short* xpd = (unsigned short*)(ws + 32768 + 37748736);     // 35,684,352 B

  k_detect   <<<1, 256, 0, stream>>>((const unsigned short*)x, flag);
  k_style    <<<NB, 256, 0, stream>>>(style, mod_w, mod_b, flag, s_buf);
  k_weights  <<<dim3(COUT, NB), 256, 0, stream>>>(weight, s_buf, flag, Aw);
  k_transpose<<<dim3(66, NB), 256, 0, stream>>>(x, flag, xpd);
  k_gemm     <<<2048, 256, 0, stream>>>(Aw, xpd, flag, d_out);
}